// Round 3
// 71.578 us; speedup vs baseline: 1.0160x; 1.0160x over previous
//
#include <hip/hip_runtime.h>
#include <math.h>

// Gaussians covariance, MI355X. cov = s^2 * I exactly (isotropic scales,
// R orthogonal) -> problem is the exact 3-NN search over N^2 pairs.
//
// R14 (bisection round; R12/R13 both failed at absmax ~7e-6):
//  - R13 falsified the qi theory (restore changed nothing). Bug is in the
//    R12 set {coalesced staging, XOR swizzle, min3 inline-asm, sT flip}.
//  - This round: EXACT R11 structure (linear sB slots, sT [cell][iloc]
//    TSTR=257, scalar b32 reduce, +qi pack) plus ONLY the two
//    source-level-identity changes:
//    * min pairing via nested fminf (no inline asm; backend fuses to
//      v_min3_f32) -> min stream 512 -> ~256 instrs/wave if fused.
//    * coalesced staging: consecutive t -> consecutive j; same
//      (col,b)->slot layout as R11, so sB contents are bit-identical.
//  - If this passes: R15 re-adds sT flip, R16 the XOR swizzle (isolate).
// NOTE: ~41us of the timed window is the harness's 256MiB ws poison fill.

#define N_PTS 12288
#define CHUNK 512               // j's per chunk
#define NCH   (N_PTS / CHUNK)   // 24 chunks
#define CELLJ 16                // consecutive j's per cell; 32 cells/chunk
#define IBLK  256               // i's per pass-A block
#define NIB   (N_PTS / IBLK)    // 48
#define TSTR  257               // LDS transpose stride (dwords)
#define CMASK 1023u             // 10-bit cell id

typedef _Float16 half8  __attribute__((ext_vector_type(8)));
typedef float    f32x16 __attribute__((ext_vector_type(16)));

__device__ __forceinline__ void ins4(float d, float& a0, float& a1,
                                     float& a2, float& a3) {
    // insert d into sorted a0<=a1<=a2<=a3, keep 4 smallest (4 VALU)
    const float n0 = fminf(a0, d);
    const float n1 = __builtin_amdgcn_fmed3f(a0, a1, d);
    const float n2 = __builtin_amdgcn_fmed3f(a1, a2, d);
    const float n3 = __builtin_amdgcn_fmed3f(a2, a3, d);
    a0 = n0; a1 = n1; a2 = n2; a3 = n3;
}

__global__ __launch_bounds__(256, 4) void cellmin_mfma(
    const float* __restrict__ pts, float4* __restrict__ ws4)
{
    // union: sB (16 b-iters x 64 lane-slots x 8 halves = 16KB) during MFMA,
    // then sT (32 cells x 256 i, stride TSTR = 32.9KB) for the transpose
    __shared__ __align__(16) unsigned char shmem[32 * TSTR * 4];
    _Float16* sB = (_Float16*)shmem;
    float*    sT = (float*)shmem;

    const int t    = threadIdx.x;
    const int iblk = blockIdx.x * IBLK;
    const int g    = blockIdx.y;           // chunk 0..23

    // ---- stage B fragments: COALESCED (consecutive t -> consecutive j) ----
    // cell col holds j = g*512 + col*16 + b, col = idx>>4, b = idx&15.
    // Slot layout IDENTICAL to R11: slot = b*64 + col (s0), +32 (s1).
    // K slots (h=0): k0-2 = -bh(xyz) (vs ah), k3-5 = -bh(xyz) (vs al),
    //                k6-7 = -bl(x,y) (vs ah)
    //        (h=1): k8 = -bl_z (vs ah_z), k9 = qh, k10 = ql (vs 1), rest 0
    #pragma unroll
    for (int it = 0; it < 2; ++it) {
        const int idx = t + it * 256;
        const int col = idx >> 4, b = idx & 15;
        const int j = g * CHUNK + idx;       // == g*512 + col*16 + b
        const float x = pts[3 * j + 0], y = pts[3 * j + 1], z = pts[3 * j + 2];
        const _Float16 bhx = (_Float16)x, bhy = (_Float16)y, bhz = (_Float16)z;
        const _Float16 blx = (_Float16)(x - (float)bhx);
        const _Float16 bly = (_Float16)(y - (float)bhy);
        const _Float16 blz = (_Float16)(z - (float)bhz);
        const float q = 0.5f * fmaf(z, z, fmaf(y, y, x * x));
        const _Float16 qh = (_Float16)q;
        const _Float16 ql = (_Float16)(q - (float)qh);
        half8 s0;
        s0[0] = -bhx; s0[1] = -bhy; s0[2] = -bhz;
        s0[3] = -bhx; s0[4] = -bhy; s0[5] = -bhz;
        s0[6] = -blx; s0[7] = -bly;
        half8 s1 = (_Float16)0;
        s1[0] = -blz; s1[1] = qh; s1[2] = ql;
        *(half8*)&sB[(b * 64 + col) * 8]      = s0;   // h=0 lanes
        *(half8*)&sB[(b * 64 + 32 + col) * 8] = s1;   // h=1 lanes
    }

    // own-i q (thread t owns i = iblk + t for the reduce/store phase)
    float qi_t;
    {
        const float x = pts[3 * (iblk + t) + 0];
        const float y = pts[3 * (iblk + t) + 1];
        const float z = pts[3 * (iblk + t) + 2];
        qi_t = 0.5f * fmaf(z, z, fmaf(y, y, x * x));
    }

    // ---- A fragments: wave w owns i-tiles 2w, 2w+1 (32 i's each) ----
    const int lane = t & 63;
    const int w    = t >> 6;
    const int m    = lane & 31;    // A row / D col == cell lane
    const int h    = lane >> 5;    // k-half

    half8  afr[2];
    f32x16 mn[2];
    #pragma unroll
    for (int tau = 0; tau < 2; ++tau) {
        const int i = iblk + (2 * w + tau) * 32 + m;
        const float x = pts[3 * i + 0], y = pts[3 * i + 1], z = pts[3 * i + 2];
        const _Float16 ahx = (_Float16)x, ahy = (_Float16)y, ahz = (_Float16)z;
        const _Float16 alx = (_Float16)(x - (float)ahx);
        const _Float16 aly = (_Float16)(y - (float)ahy);
        const _Float16 alz = (_Float16)(z - (float)ahz);
        half8 a = (_Float16)0;
        if (h == 0) {        // k0-7: ah(xyz), al(xyz), ah(x,y)
            a[0] = ahx; a[1] = ahy; a[2] = ahz;
            a[3] = alx; a[4] = aly; a[5] = alz;
            a[6] = ahx; a[7] = ahy;
        } else {             // k8-15: ah_z, 1, 1, zeros
            a[0] = ahz; a[1] = (_Float16)1.0f; a[2] = (_Float16)1.0f;
        }
        afr[tau] = a;
        mn[tau] = INFINITY;
    }
    __syncthreads();

    const f32x16 zero16 = 0.0f;
    #pragma unroll 2
    for (int b = 0; b < 16; b += 2) {
        const half8 bf0 = *(const half8*)&sB[(b * 64 + lane) * 8];
        const half8 bf1 = *(const half8*)&sB[((b + 1) * 64 + lane) * 8];
        #pragma unroll
        for (int tau = 0; tau < 2; ++tau) {
            const f32x16 d0 = __builtin_amdgcn_mfma_f32_32x32x16_f16(
                afr[tau], bf0, zero16, 0, 0, 0);
            const f32x16 d1 = __builtin_amdgcn_mfma_f32_32x32x16_f16(
                afr[tau], bf1, zero16, 0, 0, 0);
            #pragma unroll
            for (int r = 0; r < 16; ++r)
                mn[tau][r] = fminf(fminf(d0[r], d1[r]), mn[tau][r]);
        }
    }
    __syncthreads();   // done with sB; reuse as transpose buffer

    // ---- transpose through LDS: sT[cell][i_loc], stride TSTR (R11) ----
    #pragma unroll
    for (int tau = 0; tau < 2; ++tau) {
        #pragma unroll
        for (int r = 0; r < 16; ++r) {
            const int row = (r & 3) + 8 * (r >> 2) + 4 * h;
            sT[m * TSTR + (2 * w + tau) * 32 + row] = mn[tau][r];
        }
    }
    __syncthreads();

    // ---- per-i reduce: 32 cells -> top-4 packed, ONE float4 store (R11) --
    float t0 = INFINITY, t1 = INFINITY, t2 = INFINITY, t3 = INFINITY;
    #pragma unroll 8
    for (int c = 0; c < 32; ++c) {
        const float v = sT[c * TSTR + t] + qi_t;
        const unsigned cid = (unsigned)(g * 32 + c);
        const float pv = __uint_as_float((__float_as_uint(v) & ~CMASK) | cid);
        ins4(pv, t0, t1, t2, t3);
    }
    ws4[(size_t)g * N_PTS + (iblk + t)] = make_float4(t0, t1, t2, t3);
}

// 1536 single-wave blocks: 8 i's per wave, 8 workers per i.
__global__ __launch_bounds__(64) void knn_finalize(
    const float4* __restrict__ ws4, const float* __restrict__ pts,
    float* __restrict__ out)
{
    __shared__ float sS[8];
    const int lane  = threadIdx.x;
    const int il    = lane & 7;          // i_loc 0..7
    const int w     = lane >> 3;         // worker 0..7
    const int ibase = blockIdx.x * 8;
    const int i     = ibase + il;

    // phase 1: worker w scans chunks [3w, 3w+3): 3 coalesced float4 loads
    float c0 = INFINITY, c1 = INFINITY, c2 = INFINITY, c3 = INFINITY;
    #pragma unroll
    for (int k = 0; k < 3; ++k) {
        const float4 v = ws4[(size_t)(3 * w + k) * N_PTS + i];
        ins4(v.x, c0, c1, c2, c3);
        ins4(v.y, c0, c1, c2, c3);
        ins4(v.z, c0, c1, c2, c3);
        ins4(v.w, c0, c1, c2, c3);
    }

    // phase 2: butterfly merge across the worker dimension (lane bits 3-5)
    #pragma unroll
    for (int mask = 8; mask < 64; mask <<= 1) {
        const float p0 = __shfl_xor(c0, mask);
        const float p1 = __shfl_xor(c1, mask);
        const float p2 = __shfl_xor(c2, mask);
        const float p3 = __shfl_xor(c3, mask);
        ins4(p0, c0, c1, c2, c3);
        ins4(p1, c0, c1, c2, c3);
        ins4(p2, c0, c1, c2, c3);
        ins4(p3, c0, c1, c2, c3);
    }
    // all lanes of i-group il now hold the global top-4 cells for i

    const float px = pts[3 * i + 0];
    const float py = pts[3 * i + 1];
    const float pz = pts[3 * i + 2];

    // phase 3: exact diff-form rescan; worker w takes 2 consecutive j's
    // per candidate cell (16 consecutive j's per cell)
    float b0 = INFINITY, b1 = INFINITY, b2 = INFINITY, b3 = INFINITY;
    const unsigned cells[4] = {
        __float_as_uint(c0) & CMASK, __float_as_uint(c1) & CMASK,
        __float_as_uint(c2) & CMASK, __float_as_uint(c3) & CMASK };
    #pragma unroll
    for (int q = 0; q < 4; ++q) {
        const int cid = (int)cells[q];
        const int jb  = (cid >> 5) * CHUNK + (cid & 31) * CELLJ + w * 2;
        #pragma unroll
        for (int n = 0; n < 2; ++n) {
            const int j = jb + n;
            const float dx = px - pts[3 * j + 0];
            const float dy = py - pts[3 * j + 1];
            const float dz = pz - pts[3 * j + 2];
            const float d2 = fmaf(dz, dz, fmaf(dy, dy, dx * dx));
            ins4(d2, b0, b1, b2, b3);        // j==i gives exactly 0
        }
    }

    // phase 4: butterfly merge of the rescan top-4s
    #pragma unroll
    for (int mask = 8; mask < 64; mask <<= 1) {
        const float p0 = __shfl_xor(b0, mask);
        const float p1 = __shfl_xor(b1, mask);
        const float p2 = __shfl_xor(b2, mask);
        const float p3 = __shfl_xor(b3, mask);
        ins4(p0, b0, b1, b2, b3);
        ins4(p1, b0, b1, b2, b3);
        ins4(p2, b0, b1, b2, b3);
        ins4(p3, b0, b1, b2, b3);
    }

    // b0 == 0 is the self pair; b1..b3 are the true 3-NN squared distances
    if (w == 0) {
        const float d0 = sqrtf(b1);
        const float d1 = sqrtf(b2);
        const float d2 = sqrtf(b3);
        float mean = fmaxf((d0 + d1 + d2) * (1.0f / 3.0f), 1e-5f);
        const float s = 0.001f * mean;
        sS[il] = s * s;
    }
    __syncthreads();

    // coalesced s^2 * I store: 72 floats for this wave's 8 i's
    for (int k = lane; k < 72; k += 64) {
        const int i2 = k / 9, r = k % 9;
        const float v = (r == 0 || r == 4 || r == 8) ? sS[i2] : 0.0f;
        out[(size_t)(ibase + i2) * 9 + r] = v;
    }
}

extern "C" void kernel_launch(void* const* d_in, const int* in_sizes, int n_in,
                              void* d_out, int out_size, void* d_ws, size_t ws_size,
                              hipStream_t stream) {
    const float* pts = (const float*)d_in[0];   // (N, 3) float32
    // d_in[1] = quaternions: algebraically irrelevant (cov = s^2 * I)
    float4* ws4 = (float4*)d_ws;                // 24 * 12288 * 16B = 4.7 MB
    float*  out = (float*)d_out;                // (N, 3, 3) float32

    cellmin_mfma<<<dim3(NIB, NCH), dim3(256), 0, stream>>>(pts, ws4);
    knn_finalize<<<dim3(N_PTS / 8), dim3(64), 0, stream>>>(ws4, pts, out);
}

// Round 4
// 67.391 us; speedup vs baseline: 1.0791x; 1.0621x over previous
//
#include <hip/hip_runtime.h>
#include <math.h>

// Gaussians covariance, MI355X. cov = s^2 * I exactly (isotropic scales,
// R orthogonal) -> problem is the exact 3-NN search over N^2 pairs.
//
// R15 (= R14 with grid-packing fix; R14 passed at 71.6us):
//  - THEORY: cellmin's 1152 blocks vs 1024 resident slots (4/CU) forces a
//    second straggler round of 128 blocks at 12.5% utilization (~1.8x
//    stretch) -- this, not the instruction stream, is the dominant gap
//    vs the pipe model.
//  - FIX: CELLJ 16 -> 24, CHUNK 512 -> 768, NCH 24 -> 16. Grid = 48x16 =
//    768 blocks = EXACTLY 3 blocks/CU (8 XCD x 96), one perfectly even
//    round. Cells/chunk stays 32 (MFMA width); total cells 512 (10-bit
//    pack unchanged). Larger cells = MORE rescan candidates (96 vs 64),
//    algorithmically safer; the top-4-cells-contain-3NN argument is
//    CELLJ-independent.
//  - __launch_bounds__(256,3): VGPR cap 128 -> ~170, no spill risk.
//  - ws4 shrinks 4.7 -> 3.1 MB; finalize: 2 chunk-loads + 3 rescan j's
//    per worker.
//  - KEPT from R14: coalesced staging, nested-fminf min pairing, R11
//    sB/sT layouts (sT flip + XOR swizzle permanently excluded -- one of
//    them was the R12/R13 correctness bug).
// NOTE: ~41us of the timed window is the harness's 256MiB ws poison fill.

#define N_PTS 12288
#define CHUNK 768               // j's per chunk
#define NCH   (N_PTS / CHUNK)   // 16 chunks
#define CELLJ 24                // consecutive j's per cell; 32 cells/chunk
#define IBLK  256               // i's per pass-A block
#define NIB   (N_PTS / IBLK)    // 48
#define TSTR  257               // LDS transpose stride (dwords)
#define CMASK 1023u             // 10-bit cell id (512 cells used)

typedef _Float16 half8  __attribute__((ext_vector_type(8)));
typedef float    f32x16 __attribute__((ext_vector_type(16)));

__device__ __forceinline__ void ins4(float d, float& a0, float& a1,
                                     float& a2, float& a3) {
    // insert d into sorted a0<=a1<=a2<=a3, keep 4 smallest (4 VALU)
    const float n0 = fminf(a0, d);
    const float n1 = __builtin_amdgcn_fmed3f(a0, a1, d);
    const float n2 = __builtin_amdgcn_fmed3f(a1, a2, d);
    const float n3 = __builtin_amdgcn_fmed3f(a2, a3, d);
    a0 = n0; a1 = n1; a2 = n2; a3 = n3;
}

__global__ __launch_bounds__(256, 3) void cellmin_mfma(
    const float* __restrict__ pts, float4* __restrict__ ws4)
{
    // union: sB (24 b-iters x 64 lane-slots x 8 halves = 24KB) during MFMA,
    // then sT (32 cells x 256 i, stride TSTR = 32.9KB) for the transpose
    __shared__ __align__(16) unsigned char shmem[32 * TSTR * 4];
    _Float16* sB = (_Float16*)shmem;
    float*    sT = (float*)shmem;

    const int t    = threadIdx.x;
    const int iblk = blockIdx.x * IBLK;
    const int g    = blockIdx.y;           // chunk 0..15

    // ---- stage B fragments: COALESCED (consecutive t -> consecutive j) ----
    // cell col holds j = g*768 + col*24 + b, col = idx/24, b = idx%24.
    // Slot layout: slot = b*64 + col (s0), +32 (s1)  [R11 linear layout]
    // K slots (h=0): k0-2 = -bh(xyz) (vs ah), k3-5 = -bh(xyz) (vs al),
    //                k6-7 = -bl(x,y) (vs ah)
    //        (h=1): k8 = -bl_z (vs ah_z), k9 = qh, k10 = ql (vs 1), rest 0
    #pragma unroll
    for (int it = 0; it < 3; ++it) {
        const int idx = t + it * 256;
        const int col = idx / CELLJ, b = idx % CELLJ;
        const int j = g * CHUNK + idx;       // == g*768 + col*24 + b
        const float x = pts[3 * j + 0], y = pts[3 * j + 1], z = pts[3 * j + 2];
        const _Float16 bhx = (_Float16)x, bhy = (_Float16)y, bhz = (_Float16)z;
        const _Float16 blx = (_Float16)(x - (float)bhx);
        const _Float16 bly = (_Float16)(y - (float)bhy);
        const _Float16 blz = (_Float16)(z - (float)bhz);
        const float q = 0.5f * fmaf(z, z, fmaf(y, y, x * x));
        const _Float16 qh = (_Float16)q;
        const _Float16 ql = (_Float16)(q - (float)qh);
        half8 s0;
        s0[0] = -bhx; s0[1] = -bhy; s0[2] = -bhz;
        s0[3] = -bhx; s0[4] = -bhy; s0[5] = -bhz;
        s0[6] = -blx; s0[7] = -bly;
        half8 s1 = (_Float16)0;
        s1[0] = -blz; s1[1] = qh; s1[2] = ql;
        *(half8*)&sB[(b * 64 + col) * 8]      = s0;   // h=0 lanes
        *(half8*)&sB[(b * 64 + 32 + col) * 8] = s1;   // h=1 lanes
    }

    // own-i q (thread t owns i = iblk + t for the reduce/store phase)
    float qi_t;
    {
        const float x = pts[3 * (iblk + t) + 0];
        const float y = pts[3 * (iblk + t) + 1];
        const float z = pts[3 * (iblk + t) + 2];
        qi_t = 0.5f * fmaf(z, z, fmaf(y, y, x * x));
    }

    // ---- A fragments: wave w owns i-tiles 2w, 2w+1 (32 i's each) ----
    const int lane = t & 63;
    const int w    = t >> 6;
    const int m    = lane & 31;    // A row / D col == cell lane
    const int h    = lane >> 5;    // k-half

    half8  afr[2];
    f32x16 mn[2];
    #pragma unroll
    for (int tau = 0; tau < 2; ++tau) {
        const int i = iblk + (2 * w + tau) * 32 + m;
        const float x = pts[3 * i + 0], y = pts[3 * i + 1], z = pts[3 * i + 2];
        const _Float16 ahx = (_Float16)x, ahy = (_Float16)y, ahz = (_Float16)z;
        const _Float16 alx = (_Float16)(x - (float)ahx);
        const _Float16 aly = (_Float16)(y - (float)ahy);
        const _Float16 alz = (_Float16)(z - (float)ahz);
        half8 a = (_Float16)0;
        if (h == 0) {        // k0-7: ah(xyz), al(xyz), ah(x,y)
            a[0] = ahx; a[1] = ahy; a[2] = ahz;
            a[3] = alx; a[4] = aly; a[5] = alz;
            a[6] = ahx; a[7] = ahy;
        } else {             // k8-15: ah_z, 1, 1, zeros
            a[0] = ahz; a[1] = (_Float16)1.0f; a[2] = (_Float16)1.0f;
        }
        afr[tau] = a;
        mn[tau] = INFINITY;
    }
    __syncthreads();

    const f32x16 zero16 = 0.0f;
    #pragma unroll 2
    for (int b = 0; b < CELLJ; b += 2) {
        const half8 bf0 = *(const half8*)&sB[(b * 64 + lane) * 8];
        const half8 bf1 = *(const half8*)&sB[((b + 1) * 64 + lane) * 8];
        #pragma unroll
        for (int tau = 0; tau < 2; ++tau) {
            const f32x16 d0 = __builtin_amdgcn_mfma_f32_32x32x16_f16(
                afr[tau], bf0, zero16, 0, 0, 0);
            const f32x16 d1 = __builtin_amdgcn_mfma_f32_32x32x16_f16(
                afr[tau], bf1, zero16, 0, 0, 0);
            #pragma unroll
            for (int r = 0; r < 16; ++r)
                mn[tau][r] = fminf(fminf(d0[r], d1[r]), mn[tau][r]);
        }
    }
    __syncthreads();   // done with sB; reuse as transpose buffer

    // ---- transpose through LDS: sT[cell][i_loc], stride TSTR ----
    #pragma unroll
    for (int tau = 0; tau < 2; ++tau) {
        #pragma unroll
        for (int r = 0; r < 16; ++r) {
            const int row = (r & 3) + 8 * (r >> 2) + 4 * h;
            sT[m * TSTR + (2 * w + tau) * 32 + row] = mn[tau][r];
        }
    }
    __syncthreads();

    // ---- per-i reduce: 32 cells -> top-4 packed, ONE float4 store ----
    float t0 = INFINITY, t1 = INFINITY, t2 = INFINITY, t3 = INFINITY;
    #pragma unroll 8
    for (int c = 0; c < 32; ++c) {
        const float v = sT[c * TSTR + t] + qi_t;
        const unsigned cid = (unsigned)(g * 32 + c);
        const float pv = __uint_as_float((__float_as_uint(v) & ~CMASK) | cid);
        ins4(pv, t0, t1, t2, t3);
    }
    ws4[(size_t)g * N_PTS + (iblk + t)] = make_float4(t0, t1, t2, t3);
}

// 1536 single-wave blocks: 8 i's per wave, 8 workers per i.
__global__ __launch_bounds__(64) void knn_finalize(
    const float4* __restrict__ ws4, const float* __restrict__ pts,
    float* __restrict__ out)
{
    __shared__ float sS[8];
    const int lane  = threadIdx.x;
    const int il    = lane & 7;          // i_loc 0..7
    const int w     = lane >> 3;         // worker 0..7
    const int ibase = blockIdx.x * 8;
    const int i     = ibase + il;

    // phase 1: worker w scans chunks [2w, 2w+2): 2 coalesced float4 loads
    float c0 = INFINITY, c1 = INFINITY, c2 = INFINITY, c3 = INFINITY;
    #pragma unroll
    for (int k = 0; k < 2; ++k) {
        const float4 v = ws4[(size_t)(2 * w + k) * N_PTS + i];
        ins4(v.x, c0, c1, c2, c3);
        ins4(v.y, c0, c1, c2, c3);
        ins4(v.z, c0, c1, c2, c3);
        ins4(v.w, c0, c1, c2, c3);
    }

    // phase 2: butterfly merge across the worker dimension (lane bits 3-5)
    #pragma unroll
    for (int mask = 8; mask < 64; mask <<= 1) {
        const float p0 = __shfl_xor(c0, mask);
        const float p1 = __shfl_xor(c1, mask);
        const float p2 = __shfl_xor(c2, mask);
        const float p3 = __shfl_xor(c3, mask);
        ins4(p0, c0, c1, c2, c3);
        ins4(p1, c0, c1, c2, c3);
        ins4(p2, c0, c1, c2, c3);
        ins4(p3, c0, c1, c2, c3);
    }
    // all lanes of i-group il now hold the global top-4 cells for i

    const float px = pts[3 * i + 0];
    const float py = pts[3 * i + 1];
    const float pz = pts[3 * i + 2];

    // phase 3: exact diff-form rescan; worker w takes 3 consecutive j's
    // per candidate cell (24 consecutive j's per cell)
    float b0 = INFINITY, b1 = INFINITY, b2 = INFINITY, b3 = INFINITY;
    const unsigned cells[4] = {
        __float_as_uint(c0) & CMASK, __float_as_uint(c1) & CMASK,
        __float_as_uint(c2) & CMASK, __float_as_uint(c3) & CMASK };
    #pragma unroll
    for (int q = 0; q < 4; ++q) {
        const int cid = (int)cells[q];
        const int jb  = (cid >> 5) * CHUNK + (cid & 31) * CELLJ + w * 3;
        #pragma unroll
        for (int n = 0; n < 3; ++n) {
            const int j = jb + n;
            const float dx = px - pts[3 * j + 0];
            const float dy = py - pts[3 * j + 1];
            const float dz = pz - pts[3 * j + 2];
            const float d2 = fmaf(dz, dz, fmaf(dy, dy, dx * dx));
            ins4(d2, b0, b1, b2, b3);        // j==i gives exactly 0
        }
    }

    // phase 4: butterfly merge of the rescan top-4s
    #pragma unroll
    for (int mask = 8; mask < 64; mask <<= 1) {
        const float p0 = __shfl_xor(b0, mask);
        const float p1 = __shfl_xor(b1, mask);
        const float p2 = __shfl_xor(b2, mask);
        const float p3 = __shfl_xor(b3, mask);
        ins4(p0, b0, b1, b2, b3);
        ins4(p1, b0, b1, b2, b3);
        ins4(p2, b0, b1, b2, b3);
        ins4(p3, b0, b1, b2, b3);
    }

    // b0 == 0 is the self pair; b1..b3 are the true 3-NN squared distances
    if (w == 0) {
        const float d0 = sqrtf(b1);
        const float d1 = sqrtf(b2);
        const float d2 = sqrtf(b3);
        float mean = fmaxf((d0 + d1 + d2) * (1.0f / 3.0f), 1e-5f);
        const float s = 0.001f * mean;
        sS[il] = s * s;
    }
    __syncthreads();

    // coalesced s^2 * I store: 72 floats for this wave's 8 i's
    for (int k = lane; k < 72; k += 64) {
        const int i2 = k / 9, r = k % 9;
        const float v = (r == 0 || r == 4 || r == 8) ? sS[i2] : 0.0f;
        out[(size_t)(ibase + i2) * 9 + r] = v;
    }
}

extern "C" void kernel_launch(void* const* d_in, const int* in_sizes, int n_in,
                              void* d_out, int out_size, void* d_ws, size_t ws_size,
                              hipStream_t stream) {
    const float* pts = (const float*)d_in[0];   // (N, 3) float32
    // d_in[1] = quaternions: algebraically irrelevant (cov = s^2 * I)
    float4* ws4 = (float4*)d_ws;                // 16 * 12288 * 16B = 3.1 MB
    float*  out = (float*)d_out;                // (N, 3, 3) float32

    cellmin_mfma<<<dim3(NIB, NCH), dim3(256), 0, stream>>>(pts, ws4);
    knn_finalize<<<dim3(N_PTS / 8), dim3(64), 0, stream>>>(ws4, pts, out);
}

// Round 6
// 66.834 us; speedup vs baseline: 1.0881x; 1.0083x over previous
//
#include <hip/hip_runtime.h>
#include <math.h>

// Gaussians covariance, MI355X. cov = s^2 * I exactly (isotropic scales,
// R orthogonal) -> problem is the exact 3-NN search over N^2 pairs.
//
// R17 (= R15 cellmin + redistributed finalize as a 2nd ordinary kernel):
//  - POST-MORTEM R16: absmax 1.475e-6 == max|ref| (s^2 of the largest
//    3-NN mean) => output was ALL ZEROS: the cooperative launch never
//    executed (graph-capture / edge-exact 768-block co-residency).
//    Phase A was byte-identical to passing R15; a logic bug would give
//    ~7e-6 (wrong neighbors, seen R12/R13). Cooperative launch is hereby
//    excluded for this harness.
//  - KEPT: the R16 finalize redistribution, now as a standalone kernel:
//    768 blocks x 256 threads, block owns 16 i's, 16 workers/i
//    (il2=lane&3, w2=lane>>2), 1 ws4 float4 load per worker, butterfly
//    masks 4..32, rescan 96 = cell q=w2>>2 x offsets (w2&3)+4k (k<6),
//    branchless cell select. vs R15 finalize: 4x workers/i, chains
//    halved -> predicted ~8us -> ~3us.
//  - cellmin: BYTE-IDENTICAL to R15 (passed, 67.4us).
// NOTE: ~40us of the timed window is the harness's 256MiB ws poison fill.

#define N_PTS 12288
#define CHUNK 768               // j's per chunk
#define NCH   (N_PTS / CHUNK)   // 16 chunks
#define CELLJ 24                // consecutive j's per cell; 32 cells/chunk
#define IBLK  256               // i's per pass-A block
#define NIB   (N_PTS / IBLK)    // 48
#define TSTR  257               // LDS transpose stride (dwords)
#define CMASK 1023u             // 10-bit cell id (512 cells used)

typedef _Float16 half8  __attribute__((ext_vector_type(8)));
typedef float    f32x16 __attribute__((ext_vector_type(16)));

__device__ __forceinline__ void ins4(float d, float& a0, float& a1,
                                     float& a2, float& a3) {
    // insert d into sorted a0<=a1<=a2<=a3, keep 4 smallest (4 VALU)
    const float n0 = fminf(a0, d);
    const float n1 = __builtin_amdgcn_fmed3f(a0, a1, d);
    const float n2 = __builtin_amdgcn_fmed3f(a1, a2, d);
    const float n3 = __builtin_amdgcn_fmed3f(a2, a3, d);
    a0 = n0; a1 = n1; a2 = n2; a3 = n3;
}

__global__ __launch_bounds__(256, 3) void cellmin_mfma(
    const float* __restrict__ pts, float4* __restrict__ ws4)
{
    // union: sB (24 b-iters x 64 lane-slots x 8 halves = 24KB) during MFMA,
    // then sT (32 cells x 256 i, stride TSTR = 32.9KB) for the transpose
    __shared__ __align__(16) unsigned char shmem[32 * TSTR * 4];
    _Float16* sB = (_Float16*)shmem;
    float*    sT = (float*)shmem;

    const int t    = threadIdx.x;
    const int iblk = blockIdx.x * IBLK;
    const int g    = blockIdx.y;           // chunk 0..15

    // ---- stage B fragments: COALESCED (consecutive t -> consecutive j) ----
    // cell col holds j = g*768 + col*24 + b, col = idx/24, b = idx%24.
    // Slot layout: slot = b*64 + col (s0), +32 (s1)  [R11 linear layout]
    // K slots (h=0): k0-2 = -bh(xyz) (vs ah), k3-5 = -bh(xyz) (vs al),
    //                k6-7 = -bl(x,y) (vs ah)
    //        (h=1): k8 = -bl_z (vs ah_z), k9 = qh, k10 = ql (vs 1), rest 0
    #pragma unroll
    for (int it = 0; it < 3; ++it) {
        const int idx = t + it * 256;
        const int col = idx / CELLJ, b = idx % CELLJ;
        const int j = g * CHUNK + idx;       // == g*768 + col*24 + b
        const float x = pts[3 * j + 0], y = pts[3 * j + 1], z = pts[3 * j + 2];
        const _Float16 bhx = (_Float16)x, bhy = (_Float16)y, bhz = (_Float16)z;
        const _Float16 blx = (_Float16)(x - (float)bhx);
        const _Float16 bly = (_Float16)(y - (float)bhy);
        const _Float16 blz = (_Float16)(z - (float)bhz);
        const float q = 0.5f * fmaf(z, z, fmaf(y, y, x * x));
        const _Float16 qh = (_Float16)q;
        const _Float16 ql = (_Float16)(q - (float)qh);
        half8 s0;
        s0[0] = -bhx; s0[1] = -bhy; s0[2] = -bhz;
        s0[3] = -bhx; s0[4] = -bhy; s0[5] = -bhz;
        s0[6] = -blx; s0[7] = -bly;
        half8 s1 = (_Float16)0;
        s1[0] = -blz; s1[1] = qh; s1[2] = ql;
        *(half8*)&sB[(b * 64 + col) * 8]      = s0;   // h=0 lanes
        *(half8*)&sB[(b * 64 + 32 + col) * 8] = s1;   // h=1 lanes
    }

    // own-i q (thread t owns i = iblk + t for the reduce/store phase)
    float qi_t;
    {
        const float x = pts[3 * (iblk + t) + 0];
        const float y = pts[3 * (iblk + t) + 1];
        const float z = pts[3 * (iblk + t) + 2];
        qi_t = 0.5f * fmaf(z, z, fmaf(y, y, x * x));
    }

    // ---- A fragments: wave w owns i-tiles 2w, 2w+1 (32 i's each) ----
    const int lane = t & 63;
    const int w    = t >> 6;
    const int m    = lane & 31;    // A row / D col == cell lane
    const int h    = lane >> 5;    // k-half

    half8  afr[2];
    f32x16 mn[2];
    #pragma unroll
    for (int tau = 0; tau < 2; ++tau) {
        const int i = iblk + (2 * w + tau) * 32 + m;
        const float x = pts[3 * i + 0], y = pts[3 * i + 1], z = pts[3 * i + 2];
        const _Float16 ahx = (_Float16)x, ahy = (_Float16)y, ahz = (_Float16)z;
        const _Float16 alx = (_Float16)(x - (float)ahx);
        const _Float16 aly = (_Float16)(y - (float)ahy);
        const _Float16 alz = (_Float16)(z - (float)ahz);
        half8 a = (_Float16)0;
        if (h == 0) {        // k0-7: ah(xyz), al(xyz), ah(x,y)
            a[0] = ahx; a[1] = ahy; a[2] = ahz;
            a[3] = alx; a[4] = aly; a[5] = alz;
            a[6] = ahx; a[7] = ahy;
        } else {             // k8-15: ah_z, 1, 1, zeros
            a[0] = ahz; a[1] = (_Float16)1.0f; a[2] = (_Float16)1.0f;
        }
        afr[tau] = a;
        mn[tau] = INFINITY;
    }
    __syncthreads();

    const f32x16 zero16 = 0.0f;
    #pragma unroll 2
    for (int b = 0; b < CELLJ; b += 2) {
        const half8 bf0 = *(const half8*)&sB[(b * 64 + lane) * 8];
        const half8 bf1 = *(const half8*)&sB[((b + 1) * 64 + lane) * 8];
        #pragma unroll
        for (int tau = 0; tau < 2; ++tau) {
            const f32x16 d0 = __builtin_amdgcn_mfma_f32_32x32x16_f16(
                afr[tau], bf0, zero16, 0, 0, 0);
            const f32x16 d1 = __builtin_amdgcn_mfma_f32_32x32x16_f16(
                afr[tau], bf1, zero16, 0, 0, 0);
            #pragma unroll
            for (int r = 0; r < 16; ++r)
                mn[tau][r] = fminf(fminf(d0[r], d1[r]), mn[tau][r]);
        }
    }
    __syncthreads();   // done with sB; reuse as transpose buffer

    // ---- transpose through LDS: sT[cell][i_loc], stride TSTR ----
    #pragma unroll
    for (int tau = 0; tau < 2; ++tau) {
        #pragma unroll
        for (int r = 0; r < 16; ++r) {
            const int row = (r & 3) + 8 * (r >> 2) + 4 * h;
            sT[m * TSTR + (2 * w + tau) * 32 + row] = mn[tau][r];
        }
    }
    __syncthreads();

    // ---- per-i reduce: 32 cells -> top-4 packed, ONE float4 store ----
    float t0 = INFINITY, t1 = INFINITY, t2 = INFINITY, t3 = INFINITY;
    #pragma unroll 8
    for (int c = 0; c < 32; ++c) {
        const float v = sT[c * TSTR + t] + qi_t;
        const unsigned cid = (unsigned)(g * 32 + c);
        const float pv = __uint_as_float((__float_as_uint(v) & ~CMASK) | cid);
        ins4(pv, t0, t1, t2, t3);
    }
    ws4[(size_t)g * N_PTS + (iblk + t)] = make_float4(t0, t1, t2, t3);
}

// 768 blocks x 256 threads: block owns 16 i's, 16 workers per i.
__global__ __launch_bounds__(256) void knn_finalize(
    const float4* __restrict__ ws4, const float* __restrict__ pts,
    float* __restrict__ out)
{
    __shared__ float sS[16];
    const int t    = threadIdx.x;
    const int lane = t & 63;
    const int w    = t >> 6;             // wave 0..3
    const int bid  = blockIdx.x;         // 0..767
    const int il2  = lane & 3;           // i-slot within wave
    const int w2   = lane >> 2;          // worker 0..15
    const int i    = bid * 16 + w * 4 + il2;

    // phase 1: worker w2 loads chunk w2's top-4 for i (one float4)
    float c0 = INFINITY, c1 = INFINITY, c2 = INFINITY, c3 = INFINITY;
    {
        const float4 v = ws4[(size_t)w2 * N_PTS + i];
        ins4(v.x, c0, c1, c2, c3);
        ins4(v.y, c0, c1, c2, c3);
        ins4(v.z, c0, c1, c2, c3);
        ins4(v.w, c0, c1, c2, c3);
    }

    // phase 2: butterfly merge across the worker dim (lane bits 2-5)
    #pragma unroll
    for (int mask = 4; mask < 64; mask <<= 1) {
        const float p0 = __shfl_xor(c0, mask);
        const float p1 = __shfl_xor(c1, mask);
        const float p2 = __shfl_xor(c2, mask);
        const float p3 = __shfl_xor(c3, mask);
        ins4(p0, c0, c1, c2, c3);
        ins4(p1, c0, c1, c2, c3);
        ins4(p2, c0, c1, c2, c3);
        ins4(p3, c0, c1, c2, c3);
    }
    // all 16 workers of i-group il2 now hold the global top-4 cells for i

    const float px = pts[3 * i + 0];
    const float py = pts[3 * i + 1];
    const float pz = pts[3 * i + 2];

    // phase 3: exact diff-form rescan. 96 candidates = 4 cells x 24 j.
    // worker w2: cell q = w2>>2, j-offsets (w2&3) + 4k, k<6.
    // branchless cell select (no runtime-indexed array -> no scratch):
    float b0 = INFINITY, b1 = INFINITY, b2 = INFINITY, b3 = INFINITY;
    {
        const int q = w2 >> 2;
        const float cv_lo = (q & 2) ? c2 : c0;
        const float cv_hi = (q & 2) ? c3 : c1;
        const float cv    = (q & 1) ? cv_hi : cv_lo;
        const int   cid   = (int)(__float_as_uint(cv) & CMASK);
        const int   jb    = (cid >> 5) * CHUNK + (cid & 31) * CELLJ + (w2 & 3);
        #pragma unroll
        for (int k = 0; k < 6; ++k) {
            const int j = jb + 4 * k;
            const float dx = px - pts[3 * j + 0];
            const float dy = py - pts[3 * j + 1];
            const float dz = pz - pts[3 * j + 2];
            const float d2 = fmaf(dz, dz, fmaf(dy, dy, dx * dx));
            ins4(d2, b0, b1, b2, b3);        // j==i gives exactly 0
        }
    }

    // phase 4: butterfly merge of the rescan top-4s
    #pragma unroll
    for (int mask = 4; mask < 64; mask <<= 1) {
        const float p0 = __shfl_xor(b0, mask);
        const float p1 = __shfl_xor(b1, mask);
        const float p2 = __shfl_xor(b2, mask);
        const float p3 = __shfl_xor(b3, mask);
        ins4(p0, b0, b1, b2, b3);
        ins4(p1, b0, b1, b2, b3);
        ins4(p2, b0, b1, b2, b3);
        ins4(p3, b0, b1, b2, b3);
    }

    // b0 == 0 is the self pair; b1..b3 are the true 3-NN squared distances
    if (w2 == 0) {
        const float d0 = sqrtf(b1);
        const float d1 = sqrtf(b2);
        const float d2 = sqrtf(b3);
        float mean = fmaxf((d0 + d1 + d2) * (1.0f / 3.0f), 1e-5f);
        const float s = 0.001f * mean;
        sS[w * 4 + il2] = s * s;
    }
    __syncthreads();

    // coalesced s^2 * I store: 144 floats for this block's 16 i's
    for (int k = t; k < 144; k += 256) {
        const int i3 = k / 9, r = k % 9;
        const float v = (r == 0 || r == 4 || r == 8) ? sS[i3] : 0.0f;
        out[(size_t)(bid * 16 + i3) * 9 + r] = v;
    }
}

extern "C" void kernel_launch(void* const* d_in, const int* in_sizes, int n_in,
                              void* d_out, int out_size, void* d_ws, size_t ws_size,
                              hipStream_t stream) {
    const float* pts = (const float*)d_in[0];   // (N, 3) float32
    // d_in[1] = quaternions: algebraically irrelevant (cov = s^2 * I)
    float4* ws4 = (float4*)d_ws;                // 16 * 12288 * 16B = 3.1 MB
    float*  out = (float*)d_out;                // (N, 3, 3) float32

    cellmin_mfma<<<dim3(NIB, NCH), dim3(256), 0, stream>>>(pts, ws4);
    knn_finalize<<<dim3(N_PTS / 16), dim3(256), 0, stream>>>(ws4, pts, out);
}